// Round 8
// baseline (542.322 us; speedup 1.0000x reference)
//
#include <hip/hip_runtime.h>

// PositionWiseSpatialAttention — fused flash-style, MI355X gfx950.  R8.
//
// R5/R6/R7 all ~117-124us with every pipe <40% busy and occ 17-27% ->
// latency-bound at 12 waves/CU; intra-block restructures don't move it.
// R8: K-SPLIT ACROSS WAVE GROUPS.  512-thr blocks, 8 waves: group 0
// (waves 0-3) handles keys 0-511, group 1 (waves 4-7) keys 512-1023,
// each with its own 19456B staging buffer and 16-tile loop.  Partial
// O^T and l are exact sums -> combined via LDS at the end (no online
// rescale).  Grid stays 768 -> 3 blocks x 8 waves = 24 waves/CU (2x).
// __launch_bounds__(512,6) forces VGPR<=85 so 3 blocks/CU fit.
// Keeps: XCD swizzle (R7 win: FETCH 111->44MB), R6 inner loop (single
// ST accumulator, O0/O1, VGPR 76), 3-term split bf16 numerics, exp2.

#define NB    8
#define NT    12
#define NNODE 1024
#define ND    64
#define XROW  768   /* NT*ND */

typedef __bf16 bf16x8  __attribute__((ext_vector_type(8)));
typedef __bf16 bf16x2  __attribute__((ext_vector_type(2)));
typedef float  floatx4 __attribute__((ext_vector_type(4)));
typedef float  floatx16 __attribute__((ext_vector_type(16)));
typedef unsigned uintx4 __attribute__((ext_vector_type(4)));

#define MFMA32(a,b,c) __builtin_amdgcn_mfma_f32_32x32x16_bf16((a),(b),(c),0,0,0)
#define QSCALE 0.18033688011112042f   /* 0.125 * log2(e) */

#define KSTRIDE 72    /* bf16 per K row (d-major), 144 B */
#define VSTRIDE 40    /* bf16 per V row (key-major), 80 B */
#define OFF_KHI 0
#define OFF_KLO 4608
#define OFF_VHI 9216
#define OFF_VLO 14336
#define BUFBYTES 19456
#define SMEM_BYTES (2*BUFBYTES)   /* 38912; combine overlay 33792 fits */

struct bfpair { __bf16 h, l; };

__device__ __forceinline__ bfpair split1(float f) {
    bfpair r;
    __bf16 hb = (__bf16)f;
    float hf = __builtin_bit_cast(float,
                   (unsigned)__builtin_bit_cast(unsigned short, hb) << 16);
    r.h = hb;
    r.l = (__bf16)(f - hf);
    return r;
}

__device__ __forceinline__ unsigned pk2(__bf16 a, __bf16 b) {
    bf16x2 t; t[0] = a; t[1] = b;
    return __builtin_bit_cast(unsigned, t);
}

// Assemble B-frag (k=(lane>>5)*8+j) from C-layout packed pairs via one
// half-wave exchange.  A0,A1 = C-reg group 2kc; B0,B1 = group 2kc+1.
__device__ __forceinline__ bf16x8 xchg(unsigned A0, unsigned A1,
                                       unsigned B0, unsigned B1, int L5) {
    unsigned sA = L5 ? A0 : B0;
    unsigned sB = L5 ? A1 : B1;
    unsigned rA = (unsigned)__shfl_xor((int)sA, 32);
    unsigned rB = (unsigned)__shfl_xor((int)sB, 32);
    uintx4 u;
    u[0] = L5 ? rA : A0;
    u[1] = L5 ? rB : A1;
    u[2] = L5 ? B0 : rA;
    u[3] = L5 ? B1 : rB;
    return __builtin_bit_cast(bf16x8, u);
}

__global__ void __launch_bounds__(512, 6)
spattn(const float* __restrict__ x, const float* __restrict__ adj,
       const float* __restrict__ theta, float* __restrict__ out)
{
    __shared__ __align__(16) char smem[SMEM_BYTES];

    const int tid  = threadIdx.x;
    const int wave = tid >> 6;        // 0..7
    const int grp  = wave >> 2;       // 0: keys 0-511, 1: keys 512-1023
    const int w4   = wave & 3;        // row-tile within block
    const int lane = tid & 63;
    const int q31  = lane & 31;
    const int L5   = lane >> 5;

    const int bx   = blockIdx.x;
    const int g    = bx % 96;         // XCD swizzle: XCD = bx%8 = g%8
    const int rblk = bx / 96;
    const int bb   = g / NT;
    const int tt   = g - bb * NT;
    const int row0 = rblk * 128;
    const int qglob = row0 + w4*32 + q31;
    const int keybase = grp * 512;

    const float* xbase = x + (size_t)bb * (NNODE * XROW) + tt * ND;
    char* buf = smem + grp * BUFBYTES;

    // ---- Q B-frags (hi/lo), pre-scaled: lane holds Q[qglob][dc*16+L5*8+j] --
    bf16x8 qh[4], ql[4];
    {
        const float* qsrc = xbase + (size_t)qglob * XROW;
        #pragma unroll
        for (int dc = 0; dc < 4; ++dc) {
            floatx4 f0 = *(const floatx4*)(qsrc + dc*16 + L5*8);
            floatx4 f1 = *(const floatx4*)(qsrc + dc*16 + L5*8 + 4);
            #pragma unroll
            for (int i = 0; i < 4; ++i) {
                bfpair p0 = split1(f0[i]*QSCALE);
                qh[dc][i]   = p0.h; ql[dc][i]   = p0.l;
                bfpair p1 = split1(f1[i]*QSCALE);
                qh[dc][4+i] = p1.h; ql[dc][4+i] = p1.l;
            }
        }
    }

    floatx16 O0 = {}, O1 = {};
    float lpart = 0.f;

    // staging maps within group (256 threads): K[key][d] 1x8d; V[d][key] 1x8k
    const int t8   = tid & 255;
    const int skey = t8 >> 3;
    const int sd0  = (t8 & 7) * 8;
    const int svd  = t8 >> 2;
    const int svk0 = (t8 & 3) * 8;
    floatx4 kf0, kf1;
    float vf[8];

    { // preload tile 0 of this group's K-range
        const float* ksrc = xbase + (size_t)(keybase + skey) * XROW + sd0;
        kf0 = *(const floatx4*)ksrc;
        kf1 = *(const floatx4*)(ksrc + 4);
        const float* vsrc = xbase + (size_t)(keybase + svk0) * XROW + svd;
        #pragma unroll
        for (int i = 0; i < 8; ++i) vf[i] = vsrc[i * XROW];
    }

    for (int ct = 0; ct < 16; ++ct) {
        const int key0 = keybase + ct * 32;
        __syncthreads();                       // prior tile's LDS reads done
        { // stage tile ct (in regs) into group buffer
            bf16x8 h, l;
            #pragma unroll
            for (int i = 0; i < 4; ++i) {
                bfpair p0 = split1(kf0[i]); h[i]   = p0.h; l[i]   = p0.l;
                bfpair p1 = split1(kf1[i]); h[4+i] = p1.h; l[4+i] = p1.l;
            }
            *(bf16x8*)(buf + OFF_KHI + skey*144 + sd0*2) = h;
            *(bf16x8*)(buf + OFF_KLO + skey*144 + sd0*2) = l;
            bf16x8 vh, vl;
            #pragma unroll
            for (int i = 0; i < 8; ++i) {
                bfpair p = split1(vf[i]); vh[i] = p.h; vl[i] = p.l;
            }
            *(bf16x8*)(buf + OFF_VHI + svd*80 + svk0*2) = vh;
            *(bf16x8*)(buf + OFF_VLO + svd*80 + svk0*2) = vl;
        }
        __syncthreads();                       // staging visible
        if (ct < 15) { // register prefetch of next tile
            const int nk = key0 + 32;
            const float* ksrc = xbase + (size_t)(nk + skey) * XROW + sd0;
            kf0 = *(const floatx4*)ksrc;
            kf1 = *(const floatx4*)(ksrc + 4);
            const float* vsrc = xbase + (size_t)(nk + svk0) * XROW + svd;
            #pragma unroll
            for (int i = 0; i < 8; ++i) vf[i] = vsrc[i * XROW];
        }
        // adj for this lane's query, keys key0 + rg*8 + L5*4 + 0..3
        floatx4 adjv[4];
        #pragma unroll
        for (int rg = 0; rg < 4; ++rg)
            adjv[rg] = *(const floatx4*)(adj + (size_t)qglob * NNODE
                                         + key0 + rg*8 + L5*4);

        // ---- S^T = K.Q^T (A = K-frag: m=key, k=d) ----
        floatx16 ST = {};
        #pragma unroll
        for (int dc = 0; dc < 4; ++dc) {
            bf16x8 kh = *(const bf16x8*)(buf + OFF_KHI + q31*144 + (dc*16 + L5*8)*2);
            bf16x8 kl = *(const bf16x8*)(buf + OFF_KLO + q31*144 + (dc*16 + L5*8)*2);
            ST = MFMA32(kh, qh[dc], ST);
            ST = MFMA32(kl, qh[dc], ST);
            ST = MFMA32(kh, ql[dc], ST);
        }
        // ---- P^T = adj*exp2(S^T): reg r -> key (r&3)+8*(r>>2)+4*L5 ----
        __bf16 pth[16], ptl[16];
        #pragma unroll
        for (int r = 0; r < 16; ++r) {
            float w = __builtin_amdgcn_exp2f(ST[r]);
            lpart += w;
            bfpair p = split1(adjv[r >> 2][r & 3] * w);
            pth[r] = p.h; ptl[r] = p.l;
        }
        unsigned GH[4][2], GL[4][2];
        #pragma unroll
        for (int gg = 0; gg < 4; ++gg) {
            GH[gg][0] = pk2(pth[4*gg],   pth[4*gg+1]);
            GH[gg][1] = pk2(pth[4*gg+2], pth[4*gg+3]);
            GL[gg][0] = pk2(ptl[4*gg],   ptl[4*gg+1]);
            GL[gg][1] = pk2(ptl[4*gg+2], ptl[4*gg+3]);
        }
        // ---- O^T += V^T . P^T (A = V-frag: m=d, k=key) ----
        #pragma unroll
        for (int kc = 0; kc < 2; ++kc) {
            bf16x8 bh = xchg(GH[2*kc][0], GH[2*kc][1],
                             GH[2*kc+1][0], GH[2*kc+1][1], L5);
            bf16x8 bl = xchg(GL[2*kc][0], GL[2*kc][1],
                             GL[2*kc+1][0], GL[2*kc+1][1], L5);
            {
                bf16x8 vh = *(const bf16x8*)(buf + OFF_VHI + q31*80 + (kc*16 + L5*8)*2);
                bf16x8 vl = *(const bf16x8*)(buf + OFF_VLO + q31*80 + (kc*16 + L5*8)*2);
                O0 = MFMA32(vh, bh, O0);
                O0 = MFMA32(vl, bh, O0);
                O0 = MFMA32(vh, bl, O0);
            }
            {
                bf16x8 vh = *(const bf16x8*)(buf + OFF_VHI + (32+q31)*80 + (kc*16 + L5*8)*2);
                bf16x8 vl = *(const bf16x8*)(buf + OFF_VLO + (32+q31)*80 + (kc*16 + L5*8)*2);
                O1 = MFMA32(vh, bh, O1);
                O1 = MFMA32(vl, bh, O1);
                O1 = MFMA32(vh, bl, O1);
            }
        }
    }

    // ---- cross-group combine via LDS (O and l are exact partial sums) ----
    float* CB = (float*)smem;     // overlay: 33*256 floats = 33792 B
    __syncthreads();              // all staging reads done; safe to overwrite
    if (grp == 1) {
        const int base = w4*64 + lane;
        #pragma unroll
        for (int r = 0; r < 16; ++r) CB[r*256 + base] = O0[r];
        #pragma unroll
        for (int r = 0; r < 16; ++r) CB[(16+r)*256 + base] = O1[r];
        CB[32*256 + base] = lpart;
    }
    __syncthreads();
    if (grp == 1) return;         // no more barriers below

    {
        const int base = w4*64 + lane;
        #pragma unroll
        for (int r = 0; r < 16; ++r) O0[r] += CB[r*256 + base];
        #pragma unroll
        for (int r = 0; r < 16; ++r) O1[r] += CB[(16+r)*256 + base];
        lpart += CB[32*256 + base];
    }
    float l = lpart + __shfl_xor(lpart, 32);
    float linv = 1.0f / l;

    // ---- epilogue: out^T = theta^T . (O^T*linv), relu; LDS/barrier-free --
    bf16x8 th[2][4], tlo[2][4];
    #pragma unroll
    for (int ot = 0; ot < 2; ++ot)
        #pragma unroll
        for (int kc = 0; kc < 4; ++kc)
            #pragma unroll
            for (int j = 0; j < 8; ++j) {
                float tv = theta[(size_t)(kc*16 + L5*8 + j) * ND + ot*32 + q31];
                bfpair p = split1(tv);
                th[ot][kc][j] = p.h; tlo[ot][kc][j] = p.l;
            }

    __bf16 agh[32], agl[32];
    #pragma unroll
    for (int r = 0; r < 16; ++r) {
        bfpair p = split1(O0[r] * linv);
        agh[r] = p.h; agl[r] = p.l;
    }
    #pragma unroll
    for (int r = 0; r < 16; ++r) {
        bfpair p = split1(O1[r] * linv);
        agh[16+r] = p.h; agl[16+r] = p.l;
    }
    unsigned AH[8][2], AL[8][2];
    #pragma unroll
    for (int gg = 0; gg < 8; ++gg) {
        AH[gg][0] = pk2(agh[4*gg],   agh[4*gg+1]);
        AH[gg][1] = pk2(agh[4*gg+2], agh[4*gg+3]);
        AL[gg][0] = pk2(agl[4*gg],   agl[4*gg+1]);
        AL[gg][1] = pk2(agl[4*gg+2], agl[4*gg+3]);
    }

    floatx16 OC0 = {}, OC1 = {};
    #pragma unroll
    for (int kc = 0; kc < 4; ++kc) {
        bf16x8 bh = xchg(AH[2*kc][0], AH[2*kc][1],
                         AH[2*kc+1][0], AH[2*kc+1][1], L5);
        bf16x8 bl = xchg(AL[2*kc][0], AL[2*kc][1],
                         AL[2*kc+1][0], AL[2*kc+1][1], L5);
        OC0 = MFMA32(th[0][kc], bh, OC0);
        OC1 = MFMA32(th[1][kc], bh, OC1);
        OC0 = MFMA32(tlo[0][kc], bh, OC0);
        OC1 = MFMA32(tlo[1][kc], bh, OC1);
        OC0 = MFMA32(th[0][kc], bl, OC0);
        OC1 = MFMA32(th[1][kc], bl, OC1);
    }

    float* obase = out + (size_t)bb * (NNODE * XROW) + tt * ND
                       + (size_t)qglob * XROW;
    #pragma unroll
    for (int rg = 0; rg < 4; ++rg) {
        floatx4 v0, v1;
        #pragma unroll
        for (int i = 0; i < 4; ++i) {
            float a = OC0[4*rg + i]; v0[i] = a > 0.f ? a : 0.f;
            float b = OC1[4*rg + i]; v1[i] = b > 0.f ? b : 0.f;
        }
        *(floatx4*)(obase + 8*rg + 4*L5)      = v0;
        *(floatx4*)(obase + 32 + 8*rg + 4*L5) = v1;
    }
}

extern "C" void kernel_launch(void* const* d_in, const int* in_sizes, int n_in,
                              void* d_out, int out_size, void* d_ws, size_t ws_size,
                              hipStream_t stream) {
    (void)in_sizes; (void)n_in; (void)d_ws; (void)ws_size; (void)out_size;
    const float* x     = (const float*)d_in[0];
    const float* adj   = (const float*)d_in[1];
    const float* theta = (const float*)d_in[2];
    float* out = (float*)d_out;
    spattn<<<dim3(768), dim3(512), 0, stream>>>(x, adj, theta, out);
}

// Round 9
// 225.051 us; speedup vs baseline: 2.4098x; 2.4098x over previous
//
#include <hip/hip_runtime.h>

// PositionWiseSpatialAttention — fused flash-style, MI355X gfx950.  R9.
//
// R8 post-mortem: __launch_bounds__(512,6) forced VGPR->40 => full scratch
// spill of the accumulators (FETCH+WRITE ~2GB, 484us).  K-split idea retained,
// spill eliminated:
//  * 256-thr blocks, 4 waves: waves 0-1 = keys 0-511, waves 2-3 = keys
//    512-1023; block covers 64 query rows; grid 96 x 16 = 1536.
//  * 4-wave blocks quantize occupancy per-wave/EU: VGPR<=128 -> 16 waves/CU,
//    <=102 -> 20, <=85 -> 24 (vs R6's grid-capped 12).  launch_bounds(256,4).
//  * epilogue slimmed: theta frags loaded/split per-kc inside the MFMA loop
//    (peak -48 VGPR vs R6/R7 epilogue).
//  * keeps XCD swizzle (g=bx%96; R7-verified FETCH 111->44MB), R6 inner loop,
//    3-term split bf16 numerics, exp2 w/ folded scale.
// Cross-group combine: O^T and l are exact partial sums over disjoint keys ->
// one LDS overlay write + add; group 1 exits before the epilogue.

#define NB    8
#define NT    12
#define NNODE 1024
#define ND    64
#define XROW  768   /* NT*ND */

typedef __bf16 bf16x8  __attribute__((ext_vector_type(8)));
typedef __bf16 bf16x2  __attribute__((ext_vector_type(2)));
typedef float  floatx4 __attribute__((ext_vector_type(4)));
typedef float  floatx16 __attribute__((ext_vector_type(16)));
typedef unsigned uintx4 __attribute__((ext_vector_type(4)));

#define MFMA32(a,b,c) __builtin_amdgcn_mfma_f32_32x32x16_bf16((a),(b),(c),0,0,0)
#define QSCALE 0.18033688011112042f   /* 0.125 * log2(e) */

#define OFF_KHI 0
#define OFF_KLO 4608
#define OFF_VHI 9216
#define OFF_VLO 14336
#define BUFBYTES 19456
#define SMEM_BYTES (2*BUFBYTES)   /* 38912; combine overlay 16896 B fits */

struct bfpair { __bf16 h, l; };

__device__ __forceinline__ bfpair split1(float f) {
    bfpair r;
    __bf16 hb = (__bf16)f;
    float hf = __builtin_bit_cast(float,
                   (unsigned)__builtin_bit_cast(unsigned short, hb) << 16);
    r.h = hb;
    r.l = (__bf16)(f - hf);
    return r;
}

__device__ __forceinline__ unsigned pk2(__bf16 a, __bf16 b) {
    bf16x2 t; t[0] = a; t[1] = b;
    return __builtin_bit_cast(unsigned, t);
}

// Assemble B-frag (k=(lane>>5)*8+j) from C-layout packed pairs via one
// half-wave exchange.  A0,A1 = C-reg group 2kc; B0,B1 = group 2kc+1.
__device__ __forceinline__ bf16x8 xchg(unsigned A0, unsigned A1,
                                       unsigned B0, unsigned B1, int L5) {
    unsigned sA = L5 ? A0 : B0;
    unsigned sB = L5 ? A1 : B1;
    unsigned rA = (unsigned)__shfl_xor((int)sA, 32);
    unsigned rB = (unsigned)__shfl_xor((int)sB, 32);
    uintx4 u;
    u[0] = L5 ? rA : A0;
    u[1] = L5 ? rB : A1;
    u[2] = L5 ? B0 : rA;
    u[3] = L5 ? B1 : rB;
    return __builtin_bit_cast(bf16x8, u);
}

__global__ void __launch_bounds__(256, 4)
spattn(const float* __restrict__ x, const float* __restrict__ adj,
       const float* __restrict__ theta, float* __restrict__ out)
{
    __shared__ __align__(16) char smem[SMEM_BYTES];

    const int tid  = threadIdx.x;
    const int wave = tid >> 6;        // 0..3
    const int grp  = wave >> 1;       // 0: keys 0-511, 1: keys 512-1023
    const int w2   = wave & 1;        // row-tile within block
    const int lane = tid & 63;
    const int q31  = lane & 31;
    const int L5   = lane >> 5;

    const int bx   = blockIdx.x;
    const int g    = bx % 96;         // XCD swizzle: XCD = bx%8 = g%8
    const int rblk = bx / 96;         // 0..15
    const int bb   = g / NT;
    const int tt   = g - bb * NT;
    const int row0 = rblk * 64;
    const int qglob = row0 + w2*32 + q31;
    const int keybase = grp * 512;

    const float* xbase = x + (size_t)bb * (NNODE * XROW) + tt * ND;
    char* buf = smem + grp * BUFBYTES;

    // ---- Q B-frags (hi/lo), pre-scaled: lane holds Q[qglob][dc*16+L5*8+j] --
    bf16x8 qh[4], ql[4];
    {
        const float* qsrc = xbase + (size_t)qglob * XROW;
        #pragma unroll
        for (int dc = 0; dc < 4; ++dc) {
            floatx4 f0 = *(const floatx4*)(qsrc + dc*16 + L5*8);
            floatx4 f1 = *(const floatx4*)(qsrc + dc*16 + L5*8 + 4);
            #pragma unroll
            for (int i = 0; i < 4; ++i) {
                bfpair p0 = split1(f0[i]*QSCALE);
                qh[dc][i]   = p0.h; ql[dc][i]   = p0.l;
                bfpair p1 = split1(f1[i]*QSCALE);
                qh[dc][4+i] = p1.h; ql[dc][4+i] = p1.l;
            }
        }
    }

    floatx16 O0 = {}, O1 = {};
    float lpart = 0.f;

    // group-local staging (128 threads per group, 32 keys x 64 d):
    // K[key][d]: 1 key x 16 d per thread;  V[d][key]: 1 d x 16 keys per thread
    const int t7   = tid & 127;
    const int skey = t7 >> 2;            // 0..31
    const int sd0  = (t7 & 3) * 16;      // 0,16,32,48
    const int svd  = t7 >> 1;            // 0..63
    const int svk0 = (t7 & 1) * 16;      // 0,16
    floatx4 kr[4];
    float vv[16];

    { // preload tile 0 of this group's K-range
        const float* ksrc = xbase + (size_t)(keybase + skey) * XROW + sd0;
        #pragma unroll
        for (int i = 0; i < 4; ++i) kr[i] = *(const floatx4*)(ksrc + 4*i);
        const float* vsrc = xbase + (size_t)(keybase + svk0) * XROW + svd;
        #pragma unroll
        for (int i = 0; i < 16; ++i) vv[i] = vsrc[i * XROW];
    }

    for (int ct = 0; ct < 16; ++ct) {
        const int key0 = keybase + ct * 32;
        __syncthreads();                       // prior tile's LDS reads done
        { // stage tile ct (in regs) into group buffer, split hi/lo
            bf16x8 h0, h1, l0, l1;
            #pragma unroll
            for (int i = 0; i < 4; ++i) {
                bfpair pa = split1(kr[0][i]); h0[i]   = pa.h; l0[i]   = pa.l;
                bfpair pb = split1(kr[1][i]); h0[4+i] = pb.h; l0[4+i] = pb.l;
                bfpair pc = split1(kr[2][i]); h1[i]   = pc.h; l1[i]   = pc.l;
                bfpair pd = split1(kr[3][i]); h1[4+i] = pd.h; l1[4+i] = pd.l;
            }
            *(bf16x8*)(buf + OFF_KHI + skey*144 + sd0*2)      = h0;
            *(bf16x8*)(buf + OFF_KHI + skey*144 + sd0*2 + 16) = h1;
            *(bf16x8*)(buf + OFF_KLO + skey*144 + sd0*2)      = l0;
            *(bf16x8*)(buf + OFF_KLO + skey*144 + sd0*2 + 16) = l1;
            bf16x8 vh0, vh1, vl0, vl1;
            #pragma unroll
            for (int i = 0; i < 8; ++i) {
                bfpair pa = split1(vv[i]);   vh0[i] = pa.h; vl0[i] = pa.l;
                bfpair pb = split1(vv[8+i]); vh1[i] = pb.h; vl1[i] = pb.l;
            }
            *(bf16x8*)(buf + OFF_VHI + svd*80 + svk0*2)      = vh0;
            *(bf16x8*)(buf + OFF_VHI + svd*80 + svk0*2 + 16) = vh1;
            *(bf16x8*)(buf + OFF_VLO + svd*80 + svk0*2)      = vl0;
            *(bf16x8*)(buf + OFF_VLO + svd*80 + svk0*2 + 16) = vl1;
        }
        __syncthreads();                       // staging visible
        if (ct < 15) { // register prefetch of next tile
            const int nk = key0 + 32;
            const float* ksrc = xbase + (size_t)(nk + skey) * XROW + sd0;
            #pragma unroll
            for (int i = 0; i < 4; ++i) kr[i] = *(const floatx4*)(ksrc + 4*i);
            const float* vsrc = xbase + (size_t)(nk + svk0) * XROW + svd;
            #pragma unroll
            for (int i = 0; i < 16; ++i) vv[i] = vsrc[i * XROW];
        }
        // adj for this lane's query, keys key0 + rg*8 + L5*4 + 0..3
        floatx4 adjv[4];
        #pragma unroll
        for (int rg = 0; rg < 4; ++rg)
            adjv[rg] = *(const floatx4*)(adj + (size_t)qglob * NNODE
                                         + key0 + rg*8 + L5*4);

        // ---- S^T = K.Q^T (A = K-frag: m=key, k=d) ----
        floatx16 ST = {};
        #pragma unroll
        for (int dc = 0; dc < 4; ++dc) {
            bf16x8 kh = *(const bf16x8*)(buf + OFF_KHI + q31*144 + (dc*16 + L5*8)*2);
            bf16x8 kl = *(const bf16x8*)(buf + OFF_KLO + q31*144 + (dc*16 + L5*8)*2);
            ST = MFMA32(kh, qh[dc], ST);
            ST = MFMA32(kl, qh[dc], ST);
            ST = MFMA32(kh, ql[dc], ST);
        }
        // ---- P^T = adj*exp2(S^T): reg r -> key (r&3)+8*(r>>2)+4*L5 ----
        __bf16 pth[16], ptl[16];
        #pragma unroll
        for (int r = 0; r < 16; ++r) {
            float w = __builtin_amdgcn_exp2f(ST[r]);
            lpart += w;
            bfpair p = split1(adjv[r >> 2][r & 3] * w);
            pth[r] = p.h; ptl[r] = p.l;
        }
        unsigned GH[4][2], GL[4][2];
        #pragma unroll
        for (int gg = 0; gg < 4; ++gg) {
            GH[gg][0] = pk2(pth[4*gg],   pth[4*gg+1]);
            GH[gg][1] = pk2(pth[4*gg+2], pth[4*gg+3]);
            GL[gg][0] = pk2(ptl[4*gg],   ptl[4*gg+1]);
            GL[gg][1] = pk2(ptl[4*gg+2], ptl[4*gg+3]);
        }
        // ---- O^T += V^T . P^T (A = V-frag: m=d, k=key) ----
        #pragma unroll
        for (int kc = 0; kc < 2; ++kc) {
            bf16x8 bh = xchg(GH[2*kc][0], GH[2*kc][1],
                             GH[2*kc+1][0], GH[2*kc+1][1], L5);
            bf16x8 bl = xchg(GL[2*kc][0], GL[2*kc][1],
                             GL[2*kc+1][0], GL[2*kc+1][1], L5);
            {
                bf16x8 vh = *(const bf16x8*)(buf + OFF_VHI + q31*80 + (kc*16 + L5*8)*2);
                bf16x8 vl = *(const bf16x8*)(buf + OFF_VLO + q31*80 + (kc*16 + L5*8)*2);
                O0 = MFMA32(vh, bh, O0);
                O0 = MFMA32(vl, bh, O0);
                O0 = MFMA32(vh, bl, O0);
            }
            {
                bf16x8 vh = *(const bf16x8*)(buf + OFF_VHI + (32+q31)*80 + (kc*16 + L5*8)*2);
                bf16x8 vl = *(const bf16x8*)(buf + OFF_VLO + (32+q31)*80 + (kc*16 + L5*8)*2);
                O1 = MFMA32(vh, bh, O1);
                O1 = MFMA32(vl, bh, O1);
                O1 = MFMA32(vh, bl, O1);
            }
        }
    }

    // ---- cross-group combine via LDS (O and l are exact partial sums) ----
    float* CB = (float*)smem;     // overlay: 33*128 floats = 16896 B
    __syncthreads();              // all staging reads done; safe to overwrite
    if (grp == 1) {
        const int base = w2*64 + lane;
        #pragma unroll
        for (int r = 0; r < 16; ++r) CB[r*128 + base] = O0[r];
        #pragma unroll
        for (int r = 0; r < 16; ++r) CB[(16+r)*128 + base] = O1[r];
        CB[32*128 + base] = lpart;
    }
    __syncthreads();
    if (grp == 1) return;         // no more barriers below

    {
        const int base = w2*64 + lane;
        #pragma unroll
        for (int r = 0; r < 16; ++r) O0[r] += CB[r*128 + base];
        #pragma unroll
        for (int r = 0; r < 16; ++r) O1[r] += CB[(16+r)*128 + base];
        lpart += CB[32*128 + base];
    }
    float l = lpart + __shfl_xor(lpart, 32);
    float linv = 1.0f / l;

    // ---- epilogue: out^T = theta^T . (O^T*linv), relu; theta per-kc ----
    __bf16 agh[32], agl[32];
    #pragma unroll
    for (int r = 0; r < 16; ++r) {
        bfpair p = split1(O0[r] * linv);
        agh[r] = p.h; agl[r] = p.l;
    }
    #pragma unroll
    for (int r = 0; r < 16; ++r) {
        bfpair p = split1(O1[r] * linv);
        agh[16+r] = p.h; agl[16+r] = p.l;
    }
    unsigned AH[8][2], AL[8][2];
    #pragma unroll
    for (int gg = 0; gg < 8; ++gg) {
        AH[gg][0] = pk2(agh[4*gg],   agh[4*gg+1]);
        AH[gg][1] = pk2(agh[4*gg+2], agh[4*gg+3]);
        AL[gg][0] = pk2(agl[4*gg],   agl[4*gg+1]);
        AL[gg][1] = pk2(agl[4*gg+2], agl[4*gg+3]);
    }

    floatx16 OC0 = {}, OC1 = {};
    #pragma unroll
    for (int kc = 0; kc < 4; ++kc) {
        bf16x8 bh = xchg(AH[2*kc][0], AH[2*kc][1],
                         AH[2*kc+1][0], AH[2*kc+1][1], L5);
        bf16x8 bl = xchg(AL[2*kc][0], AL[2*kc][1],
                         AL[2*kc+1][0], AL[2*kc+1][1], L5);
        // theta frags for this kc only (A[m=o][k=d]), split inline
        bf16x8 t0h, t0l, t1h, t1l;
        #pragma unroll
        for (int j = 0; j < 8; ++j) {
            const float* tp = theta + (size_t)(kc*16 + L5*8 + j) * ND + q31;
            bfpair p0 = split1(tp[0]);
            t0h[j] = p0.h; t0l[j] = p0.l;
            bfpair p1 = split1(tp[32]);
            t1h[j] = p1.h; t1l[j] = p1.l;
        }
        OC0 = MFMA32(t0h, bh, OC0);
        OC1 = MFMA32(t1h, bh, OC1);
        OC0 = MFMA32(t0l, bh, OC0);
        OC1 = MFMA32(t1l, bh, OC1);
        OC0 = MFMA32(t0h, bl, OC0);
        OC1 = MFMA32(t1h, bl, OC1);
    }

    float* obase = out + (size_t)bb * (NNODE * XROW) + tt * ND
                       + (size_t)qglob * XROW;
    #pragma unroll
    for (int rg = 0; rg < 4; ++rg) {
        floatx4 v0, v1;
        #pragma unroll
        for (int i = 0; i < 4; ++i) {
            float a = OC0[4*rg + i]; v0[i] = a > 0.f ? a : 0.f;
            float b = OC1[4*rg + i]; v1[i] = b > 0.f ? b : 0.f;
        }
        *(floatx4*)(obase + 8*rg + 4*L5)      = v0;
        *(floatx4*)(obase + 32 + 8*rg + 4*L5) = v1;
    }
}

extern "C" void kernel_launch(void* const* d_in, const int* in_sizes, int n_in,
                              void* d_out, int out_size, void* d_ws, size_t ws_size,
                              hipStream_t stream) {
    (void)in_sizes; (void)n_in; (void)d_ws; (void)ws_size; (void)out_size;
    const float* x     = (const float*)d_in[0];
    const float* adj   = (const float*)d_in[1];
    const float* theta = (const float*)d_in[2];
    float* out = (float*)d_out;
    spattn<<<dim3(1536), dim3(256), 0, stream>>>(x, adj, theta, out);
}

// Round 10
// 208.836 us; speedup vs baseline: 2.5969x; 1.0776x over previous
//
#include <hip/hip_runtime.h>

// PositionWiseSpatialAttention — fused flash-style, MI355X gfx950.  R10.
//
// R10 = R9 with ONE change: __launch_bounds__(256,2).
// R8/R9 post-mortem: empirically the HIP allocator caps VGPRs at ~256/arg2
// ((256,2)->120 used, (512,6)->40, (256,4)->64) -> R9's (256,4) forced a
// 64-reg cap on a ~110-reg kernel => scratch spill (WRITE 47.6MB vs 24.6MB
// of output, FETCH +19MB, dur 177us).  With cap ~128 the kernel fits; then
// occupancy is LDS-bound: 38912B -> 4 blocks/CU = 16 waves/CU (vs R6's 12).
// Structure (R9): 256-thr blocks, waves 0-1 keys 0-511 / waves 2-3 keys
// 512-1023, 64 query rows/block, grid 96x16, exact partial-sum combine via
// LDS overlay; XCD swizzle; 3-term split bf16; exp2 w/ folded scale.

#define NB    8
#define NT    12
#define NNODE 1024
#define ND    64
#define XROW  768   /* NT*ND */

typedef __bf16 bf16x8  __attribute__((ext_vector_type(8)));
typedef __bf16 bf16x2  __attribute__((ext_vector_type(2)));
typedef float  floatx4 __attribute__((ext_vector_type(4)));
typedef float  floatx16 __attribute__((ext_vector_type(16)));
typedef unsigned uintx4 __attribute__((ext_vector_type(4)));

#define MFMA32(a,b,c) __builtin_amdgcn_mfma_f32_32x32x16_bf16((a),(b),(c),0,0,0)
#define QSCALE 0.18033688011112042f   /* 0.125 * log2(e) */

#define OFF_KHI 0
#define OFF_KLO 4608
#define OFF_VHI 9216
#define OFF_VLO 14336
#define BUFBYTES 19456
#define SMEM_BYTES (2*BUFBYTES)   /* 38912; combine overlay 16896 B fits */

struct bfpair { __bf16 h, l; };

__device__ __forceinline__ bfpair split1(float f) {
    bfpair r;
    __bf16 hb = (__bf16)f;
    float hf = __builtin_bit_cast(float,
                   (unsigned)__builtin_bit_cast(unsigned short, hb) << 16);
    r.h = hb;
    r.l = (__bf16)(f - hf);
    return r;
}

__device__ __forceinline__ unsigned pk2(__bf16 a, __bf16 b) {
    bf16x2 t; t[0] = a; t[1] = b;
    return __builtin_bit_cast(unsigned, t);
}

// Assemble B-frag (k=(lane>>5)*8+j) from C-layout packed pairs via one
// half-wave exchange.  A0,A1 = C-reg group 2kc; B0,B1 = group 2kc+1.
__device__ __forceinline__ bf16x8 xchg(unsigned A0, unsigned A1,
                                       unsigned B0, unsigned B1, int L5) {
    unsigned sA = L5 ? A0 : B0;
    unsigned sB = L5 ? A1 : B1;
    unsigned rA = (unsigned)__shfl_xor((int)sA, 32);
    unsigned rB = (unsigned)__shfl_xor((int)sB, 32);
    uintx4 u;
    u[0] = L5 ? rA : A0;
    u[1] = L5 ? rB : A1;
    u[2] = L5 ? B0 : rA;
    u[3] = L5 ? B1 : rB;
    return __builtin_bit_cast(bf16x8, u);
}

__global__ void __launch_bounds__(256, 2)
spattn(const float* __restrict__ x, const float* __restrict__ adj,
       const float* __restrict__ theta, float* __restrict__ out)
{
    __shared__ __align__(16) char smem[SMEM_BYTES];

    const int tid  = threadIdx.x;
    const int wave = tid >> 6;        // 0..3
    const int grp  = wave >> 1;       // 0: keys 0-511, 1: keys 512-1023
    const int w2   = wave & 1;        // row-tile within block
    const int lane = tid & 63;
    const int q31  = lane & 31;
    const int L5   = lane >> 5;

    const int bx   = blockIdx.x;
    const int g    = bx % 96;         // XCD swizzle: XCD = bx%8 = g%8
    const int rblk = bx / 96;         // 0..15
    const int bb   = g / NT;
    const int tt   = g - bb * NT;
    const int row0 = rblk * 64;
    const int qglob = row0 + w2*32 + q31;
    const int keybase = grp * 512;

    const float* xbase = x + (size_t)bb * (NNODE * XROW) + tt * ND;
    char* buf = smem + grp * BUFBYTES;

    // ---- Q B-frags (hi/lo), pre-scaled: lane holds Q[qglob][dc*16+L5*8+j] --
    bf16x8 qh[4], ql[4];
    {
        const float* qsrc = xbase + (size_t)qglob * XROW;
        #pragma unroll
        for (int dc = 0; dc < 4; ++dc) {
            floatx4 f0 = *(const floatx4*)(qsrc + dc*16 + L5*8);
            floatx4 f1 = *(const floatx4*)(qsrc + dc*16 + L5*8 + 4);
            #pragma unroll
            for (int i = 0; i < 4; ++i) {
                bfpair p0 = split1(f0[i]*QSCALE);
                qh[dc][i]   = p0.h; ql[dc][i]   = p0.l;
                bfpair p1 = split1(f1[i]*QSCALE);
                qh[dc][4+i] = p1.h; ql[dc][4+i] = p1.l;
            }
        }
    }

    floatx16 O0 = {}, O1 = {};
    float lpart = 0.f;

    // group-local staging (128 threads per group, 32 keys x 64 d):
    // K[key][d]: 1 key x 16 d per thread;  V[d][key]: 1 d x 16 keys per thread
    const int t7   = tid & 127;
    const int skey = t7 >> 2;            // 0..31
    const int sd0  = (t7 & 3) * 16;      // 0,16,32,48
    const int svd  = t7 >> 1;            // 0..63
    const int svk0 = (t7 & 1) * 16;      // 0,16
    floatx4 kr[4];
    float vv[16];

    { // preload tile 0 of this group's K-range
        const float* ksrc = xbase + (size_t)(keybase + skey) * XROW + sd0;
        #pragma unroll
        for (int i = 0; i < 4; ++i) kr[i] = *(const floatx4*)(ksrc + 4*i);
        const float* vsrc = xbase + (size_t)(keybase + svk0) * XROW + svd;
        #pragma unroll
        for (int i = 0; i < 16; ++i) vv[i] = vsrc[i * XROW];
    }

    for (int ct = 0; ct < 16; ++ct) {
        const int key0 = keybase + ct * 32;
        __syncthreads();                       // prior tile's LDS reads done
        { // stage tile ct (in regs) into group buffer, split hi/lo
            bf16x8 h0, h1, l0, l1;
            #pragma unroll
            for (int i = 0; i < 4; ++i) {
                bfpair pa = split1(kr[0][i]); h0[i]   = pa.h; l0[i]   = pa.l;
                bfpair pb = split1(kr[1][i]); h0[4+i] = pb.h; l0[4+i] = pb.l;
                bfpair pc = split1(kr[2][i]); h1[i]   = pc.h; l1[i]   = pc.l;
                bfpair pd = split1(kr[3][i]); h1[4+i] = pd.h; l1[4+i] = pd.l;
            }
            *(bf16x8*)(buf + OFF_KHI + skey*144 + sd0*2)      = h0;
            *(bf16x8*)(buf + OFF_KHI + skey*144 + sd0*2 + 16) = h1;
            *(bf16x8*)(buf + OFF_KLO + skey*144 + sd0*2)      = l0;
            *(bf16x8*)(buf + OFF_KLO + skey*144 + sd0*2 + 16) = l1;
            bf16x8 vh0, vh1, vl0, vl1;
            #pragma unroll
            for (int i = 0; i < 8; ++i) {
                bfpair pa = split1(vv[i]);   vh0[i] = pa.h; vl0[i] = pa.l;
                bfpair pb = split1(vv[8+i]); vh1[i] = pb.h; vl1[i] = pb.l;
            }
            *(bf16x8*)(buf + OFF_VHI + svd*80 + svk0*2)      = vh0;
            *(bf16x8*)(buf + OFF_VHI + svd*80 + svk0*2 + 16) = vh1;
            *(bf16x8*)(buf + OFF_VLO + svd*80 + svk0*2)      = vl0;
            *(bf16x8*)(buf + OFF_VLO + svd*80 + svk0*2 + 16) = vl1;
        }
        __syncthreads();                       // staging visible
        if (ct < 15) { // register prefetch of next tile
            const int nk = key0 + 32;
            const float* ksrc = xbase + (size_t)(nk + skey) * XROW + sd0;
            #pragma unroll
            for (int i = 0; i < 4; ++i) kr[i] = *(const floatx4*)(ksrc + 4*i);
            const float* vsrc = xbase + (size_t)(nk + svk0) * XROW + svd;
            #pragma unroll
            for (int i = 0; i < 16; ++i) vv[i] = vsrc[i * XROW];
        }
        // adj for this lane's query, keys key0 + rg*8 + L5*4 + 0..3
        floatx4 adjv[4];
        #pragma unroll
        for (int rg = 0; rg < 4; ++rg)
            adjv[rg] = *(const floatx4*)(adj + (size_t)qglob * NNODE
                                         + key0 + rg*8 + L5*4);

        // ---- S^T = K.Q^T (A = K-frag: m=key, k=d) ----
        floatx16 ST = {};
        #pragma unroll
        for (int dc = 0; dc < 4; ++dc) {
            bf16x8 kh = *(const bf16x8*)(buf + OFF_KHI + q31*144 + (dc*16 + L5*8)*2);
            bf16x8 kl = *(const bf16x8*)(buf + OFF_KLO + q31*144 + (dc*16 + L5*8)*2);
            ST = MFMA32(kh, qh[dc], ST);
            ST = MFMA32(kl, qh[dc], ST);
            ST = MFMA32(kh, ql[dc], ST);
        }
        // ---- P^T = adj*exp2(S^T): reg r -> key (r&3)+8*(r>>2)+4*L5 ----
        __bf16 pth[16], ptl[16];
        #pragma unroll
        for (int r = 0; r < 16; ++r) {
            float w = __builtin_amdgcn_exp2f(ST[r]);
            lpart += w;
            bfpair p = split1(adjv[r >> 2][r & 3] * w);
            pth[r] = p.h; ptl[r] = p.l;
        }
        unsigned GH[4][2], GL[4][2];
        #pragma unroll
        for (int gg = 0; gg < 4; ++gg) {
            GH[gg][0] = pk2(pth[4*gg],   pth[4*gg+1]);
            GH[gg][1] = pk2(pth[4*gg+2], pth[4*gg+3]);
            GL[gg][0] = pk2(ptl[4*gg],   ptl[4*gg+1]);
            GL[gg][1] = pk2(ptl[4*gg+2], ptl[4*gg+3]);
        }
        // ---- O^T += V^T . P^T (A = V-frag: m=d, k=key) ----
        #pragma unroll
        for (int kc = 0; kc < 2; ++kc) {
            bf16x8 bh = xchg(GH[2*kc][0], GH[2*kc][1],
                             GH[2*kc+1][0], GH[2*kc+1][1], L5);
            bf16x8 bl = xchg(GL[2*kc][0], GL[2*kc][1],
                             GL[2*kc+1][0], GL[2*kc+1][1], L5);
            {
                bf16x8 vh = *(const bf16x8*)(buf + OFF_VHI + q31*80 + (kc*16 + L5*8)*2);
                bf16x8 vl = *(const bf16x8*)(buf + OFF_VLO + q31*80 + (kc*16 + L5*8)*2);
                O0 = MFMA32(vh, bh, O0);
                O0 = MFMA32(vl, bh, O0);
                O0 = MFMA32(vh, bl, O0);
            }
            {
                bf16x8 vh = *(const bf16x8*)(buf + OFF_VHI + (32+q31)*80 + (kc*16 + L5*8)*2);
                bf16x8 vl = *(const bf16x8*)(buf + OFF_VLO + (32+q31)*80 + (kc*16 + L5*8)*2);
                O1 = MFMA32(vh, bh, O1);
                O1 = MFMA32(vl, bh, O1);
                O1 = MFMA32(vh, bl, O1);
            }
        }
    }

    // ---- cross-group combine via LDS (O and l are exact partial sums) ----
    float* CB = (float*)smem;     // overlay: 33*128 floats = 16896 B
    __syncthreads();              // all staging reads done; safe to overwrite
    if (grp == 1) {
        const int base = w2*64 + lane;
        #pragma unroll
        for (int r = 0; r < 16; ++r) CB[r*128 + base] = O0[r];
        #pragma unroll
        for (int r = 0; r < 16; ++r) CB[(16+r)*128 + base] = O1[r];
        CB[32*128 + base] = lpart;
    }
    __syncthreads();
    if (grp == 1) return;         // no more barriers below

    {
        const int base = w2*64 + lane;
        #pragma unroll
        for (int r = 0; r < 16; ++r) O0[r] += CB[r*128 + base];
        #pragma unroll
        for (int r = 0; r < 16; ++r) O1[r] += CB[(16+r)*128 + base];
        lpart += CB[32*128 + base];
    }
    float l = lpart + __shfl_xor(lpart, 32);
    float linv = 1.0f / l;

    // ---- epilogue: out^T = theta^T . (O^T*linv), relu; theta per-kc ----
    __bf16 agh[32], agl[32];
    #pragma unroll
    for (int r = 0; r < 16; ++r) {
        bfpair p = split1(O0[r] * linv);
        agh[r] = p.h; agl[r] = p.l;
    }
    #pragma unroll
    for (int r = 0; r < 16; ++r) {
        bfpair p = split1(O1[r] * linv);
        agh[16+r] = p.h; agl[16+r] = p.l;
    }
    unsigned AH[8][2], AL[8][2];
    #pragma unroll
    for (int gg = 0; gg < 8; ++gg) {
        AH[gg][0] = pk2(agh[4*gg],   agh[4*gg+1]);
        AH[gg][1] = pk2(agh[4*gg+2], agh[4*gg+3]);
        AL[gg][0] = pk2(agl[4*gg],   agl[4*gg+1]);
        AL[gg][1] = pk2(agl[4*gg+2], agl[4*gg+3]);
    }

    floatx16 OC0 = {}, OC1 = {};
    #pragma unroll
    for (int kc = 0; kc < 4; ++kc) {
        bf16x8 bh = xchg(AH[2*kc][0], AH[2*kc][1],
                         AH[2*kc+1][0], AH[2*kc+1][1], L5);
        bf16x8 bl = xchg(AL[2*kc][0], AL[2*kc][1],
                         AL[2*kc+1][0], AL[2*kc+1][1], L5);
        // theta frags for this kc only (A[m=o][k=d]), split inline
        bf16x8 t0h, t0l, t1h, t1l;
        #pragma unroll
        for (int j = 0; j < 8; ++j) {
            const float* tp = theta + (size_t)(kc*16 + L5*8 + j) * ND + q31;
            bfpair p0 = split1(tp[0]);
            t0h[j] = p0.h; t0l[j] = p0.l;
            bfpair p1 = split1(tp[32]);
            t1h[j] = p1.h; t1l[j] = p1.l;
        }
        OC0 = MFMA32(t0h, bh, OC0);
        OC1 = MFMA32(t1h, bh, OC1);
        OC0 = MFMA32(t0l, bh, OC0);
        OC1 = MFMA32(t1l, bh, OC1);
        OC0 = MFMA32(t0h, bl, OC0);
        OC1 = MFMA32(t1h, bl, OC1);
    }

    float* obase = out + (size_t)bb * (NNODE * XROW) + tt * ND
                       + (size_t)qglob * XROW;
    #pragma unroll
    for (int rg = 0; rg < 4; ++rg) {
        floatx4 v0, v1;
        #pragma unroll
        for (int i = 0; i < 4; ++i) {
            float a = OC0[4*rg + i]; v0[i] = a > 0.f ? a : 0.f;
            float b = OC1[4*rg + i]; v1[i] = b > 0.f ? b : 0.f;
        }
        *(floatx4*)(obase + 8*rg + 4*L5)      = v0;
        *(floatx4*)(obase + 32 + 8*rg + 4*L5) = v1;
    }
}

extern "C" void kernel_launch(void* const* d_in, const int* in_sizes, int n_in,
                              void* d_out, int out_size, void* d_ws, size_t ws_size,
                              hipStream_t stream) {
    (void)in_sizes; (void)n_in; (void)d_ws; (void)ws_size; (void)out_size;
    const float* x     = (const float*)d_in[0];
    const float* adj   = (const float*)d_in[1];
    const float* theta = (const float*)d_in[2];
    float* out = (float*)d_out;
    spattn<<<dim3(1536), dim3(256), 0, stream>>>(x, adj, theta, out);
}